// Round 1
// baseline (51603.973 us; speedup 1.0000x reference)
//
#include <hip/hip_runtime.h>

#define BB 32
#define SS 128
#define HH 1024
#define EE 256
#define VV 16000
#define TT 48
#define VSS (VV + SS)
#define GIN 2304
#define NEGV (-1000000.0f)

__device__ __forceinline__ float dot4(float4 a, float4 b) {
  return a.x * b.x + a.y * b.y + a.z * b.z + a.w * b.w;
}

__device__ __forceinline__ float wave_reduce_sum(float v) {
  for (int o = 32; o; o >>= 1) v += __shfl_down(v, o, 64);
  return v;
}

// ---------------- init: SOS row = 2.0, ids[:,0]=1, sampled=1, sel0=0, cnt=0 --------
__global__ __launch_bounds__(256) void k_init(float* __restrict__ out,
                                              float* __restrict__ sel0,
                                              int* __restrict__ cnt,
                                              int* __restrict__ samp) {
  const int i = blockIdx.x * 256 + threadIdx.x;
  if (i < BB * VSS) out[i] = 2.0f;
  if (i < BB * VV) cnt[i] = 0;
  if (i < BB * HH) sel0[i] = 0.0f;
  if (i < BB) {
    samp[i] = 1;
    out[(size_t)TT * BB * VSS + (size_t)i * TT] = 1.0f;
  }
}

__global__ __launch_bounds__(256) void k_count(const int* __restrict__ inp,
                                               int* __restrict__ cnt) {
  const int i = blockIdx.x * 256 + threadIdx.x;
  if (i < BB * SS) {
    const int b = i / SS;
    atomicAdd(&cnt[b * VV + inp[i]], 1);
  }
}

// ---------------- attention: th = h@Wa^T+ba ; softmax(enc.th) ; context ------------
__global__ __launch_bounds__(256) void k_attn(const float* __restrict__ hc,
                                              const float* __restrict__ Wa,
                                              const float* __restrict__ ba,
                                              const float* __restrict__ enc,
                                              float* __restrict__ ctx) {
  __shared__ float s_h[HH];
  __shared__ float s_th[HH];
  __shared__ float s_sc[SS];
  __shared__ float s_red[256];
  const int b = blockIdx.x, tid = threadIdx.x;
  const int lane = tid & 63, wv = tid >> 6;
  for (int i = tid; i < HH; i += 256) s_h[i] = hc[b * HH + i];
  __syncthreads();
  const float4* h4 = (const float4*)s_h;
  for (int j = wv; j < HH; j += 4) {
    const float4* wr = (const float4*)(Wa + (size_t)j * HH);
    float acc = 0.f;
    #pragma unroll 4
    for (int k = lane; k < HH / 4; k += 64) acc += dot4(wr[k], h4[k]);
    acc = wave_reduce_sum(acc);
    if (lane == 0) s_th[j] = acc + ba[j];
  }
  __syncthreads();
  const float4* th4 = (const float4*)s_th;
  for (int s = wv; s < SS; s += 4) {
    const float4* er = (const float4*)(enc + ((size_t)b * SS + s) * HH);
    float acc = 0.f;
    #pragma unroll 4
    for (int k = lane; k < HH / 4; k += 64) acc += dot4(er[k], th4[k]);
    acc = wave_reduce_sum(acc);
    if (lane == 0) s_sc[s] = acc;
  }
  __syncthreads();
  // softmax over S
  const float v = (tid < SS) ? s_sc[tid] : -3.4e38f;
  s_red[tid] = v;
  __syncthreads();
  for (int o = 128; o; o >>= 1) {
    if (tid < o) s_red[tid] = fmaxf(s_red[tid], s_red[tid + o]);
    __syncthreads();
  }
  const float m = s_red[0];
  __syncthreads();
  const float e = (tid < SS) ? expf(v - m) : 0.f;
  s_red[tid] = e;
  __syncthreads();
  for (int o = 128; o; o >>= 1) {
    if (tid < o) s_red[tid] += s_red[tid + o];
    __syncthreads();
  }
  const float den = s_red[0];
  __syncthreads();
  if (tid < SS) s_sc[tid] = e / den;
  __syncthreads();
  // context[b,h] = sum_s a[s] * enc[b,s,h]
  const float4* eb = (const float4*)(enc + (size_t)b * SS * HH);
  float4 acc = make_float4(0.f, 0.f, 0.f, 0.f);
  for (int s = 0; s < SS; ++s) {
    const float a = s_sc[s];
    const float4 x = eb[s * (HH / 4) + tid];
    acc.x += a * x.x; acc.y += a * x.y; acc.z += a * x.z; acc.w += a * x.w;
  }
  ((float4*)(ctx + b * HH))[tid] = acc;
}

// ---------------- GRU cell, thread per (b, j); x = [ctx, sel, emb[prev]] -----------
__global__ __launch_bounds__(256) void k_gru(const float* __restrict__ hc,
                                             const float* __restrict__ ctx,
                                             const float* __restrict__ sel,
                                             const float* __restrict__ embt,
                                             const int* __restrict__ samp,
                                             const float* __restrict__ Wih,
                                             const float* __restrict__ Whh,
                                             const float* __restrict__ bih,
                                             const float* __restrict__ bhh,
                                             float* __restrict__ hn) {
  const int gid = blockIdx.x * 256 + threadIdx.x;
  const int b = gid & 31, j = gid >> 5;
  int p = samp[b];
  int ei = (p > VV) ? 3 : p;       // strict >, as in source
  if (ei >= VV) ei = VV - 1;       // jnp OOB gather clamps
  const float4* xc = (const float4*)(ctx + b * HH);
  const float4* xs = (const float4*)(sel + b * HH);
  const float4* xe = (const float4*)(embt + (size_t)ei * EE);
  const float4* hh4 = (const float4*)(hc + b * HH);
  float gx[3], gh[3];
  #pragma unroll
  for (int gg = 0; gg < 3; ++gg) {
    const float4* wi = (const float4*)(Wih + (size_t)(gg * HH + j) * GIN);
    float a = 0.f;
    #pragma unroll 4
    for (int k = 0; k < HH / 4; ++k) a += dot4(wi[k], xc[k]);
    #pragma unroll 4
    for (int k = 0; k < HH / 4; ++k) a += dot4(wi[HH / 4 + k], xs[k]);
    #pragma unroll 4
    for (int k = 0; k < EE / 4; ++k) a += dot4(wi[2 * (HH / 4) + k], xe[k]);
    gx[gg] = a + bih[gg * HH + j];
    const float4* wh = (const float4*)(Whh + (size_t)(gg * HH + j) * HH);
    float c = 0.f;
    #pragma unroll 4
    for (int k = 0; k < HH / 4; ++k) c += dot4(wh[k], hh4[k]);
    gh[gg] = c + bhh[gg * HH + j];
  }
  const float r = 1.f / (1.f + expf(-(gx[0] + gh[0])));
  const float z = 1.f / (1.f + expf(-(gx[1] + gh[1])));
  const float n = tanhf(gx[2] + r * gh[2]);
  hn[b * HH + j] = (1.f - z) * n + z * hc[b * HH + j];
}

// ---------------- copy scores: th2 = hn@Wc^T+bc ; cseq = enc.th2 ; scatter ---------
__global__ __launch_bounds__(256) void k_copy(const float* __restrict__ hn,
                                              const float* __restrict__ Wc,
                                              const float* __restrict__ bc,
                                              const float* __restrict__ enc,
                                              const int* __restrict__ inp,
                                              float* __restrict__ cseq,
                                              float* __restrict__ cvals) {
  __shared__ float s_h[HH];
  __shared__ float s_th[HH];
  __shared__ float s_sc[SS];
  const int b = blockIdx.x, tid = threadIdx.x;
  const int lane = tid & 63, wv = tid >> 6;
  for (int i = tid; i < HH; i += 256) s_h[i] = hn[b * HH + i];
  __syncthreads();
  const float4* h4 = (const float4*)s_h;
  for (int j = wv; j < HH; j += 4) {
    const float4* wr = (const float4*)(Wc + (size_t)j * HH);
    float acc = 0.f;
    #pragma unroll 4
    for (int k = lane; k < HH / 4; k += 64) acc += dot4(wr[k], h4[k]);
    acc = wave_reduce_sum(acc);
    if (lane == 0) s_th[j] = acc + bc[j];
  }
  __syncthreads();
  const float4* th4 = (const float4*)s_th;
  for (int s = wv; s < SS; s += 4) {
    const float4* er = (const float4*)(enc + ((size_t)b * SS + s) * HH);
    float acc = 0.f;
    #pragma unroll 4
    for (int k = lane; k < HH / 4; k += 64) acc += dot4(er[k], th4[k]);
    acc = wave_reduce_sum(acc);
    if (lane == 0) {
      s_sc[s] = acc;
      cseq[b * SS + s] = acc;
    }
  }
  // zero this row's copyvals, then scatter-add copy_seq at inp positions
  for (int i = tid; i < VV; i += 256) cvals[b * VV + i] = 0.f;
  __syncthreads();
  if (tid < SS) atomicAdd(&cvals[b * VV + inp[b * SS + tid]], s_sc[tid]);
}

// ---------------- generate logits: gen = hn @ out_w^T + out_b ----------------------
__global__ __launch_bounds__(256) void k_gen(const float* __restrict__ hn,
                                             const float* __restrict__ Wo,
                                             const float* __restrict__ bo,
                                             float* __restrict__ gen) {
  const int gid = blockIdx.x * 256 + threadIdx.x;  // B*V threads
  const int b = gid & 31, v = gid >> 5;
  const float4* wr = (const float4*)(Wo + (size_t)v * HH);
  const float4* hr = (const float4*)(hn + b * HH);
  float a = 0.f;
  #pragma unroll 4
  for (int k = 0; k < HH / 4; ++k) a += dot4(wr[k], hr[k]);
  gen[(size_t)b * VV + v] = a + bo[v];
}

// ---------------- softmax over [gen | copy], log-probs, argmax, selective read -----
__global__ __launch_bounds__(256) void k_out(const float* __restrict__ gen,
                                             const float* __restrict__ cvals,
                                             const int* __restrict__ cnt,
                                             const float* __restrict__ cseq,
                                             const int* __restrict__ inp,
                                             const float* __restrict__ enc,
                                             float* __restrict__ out,
                                             float* __restrict__ seln,
                                             int* __restrict__ samp,
                                             const int t) {
  __shared__ float s_red[256];
  __shared__ int s_idx[256];
  __shared__ float s_norm[SS];
  const int b = blockIdx.x, tid = threadIdx.x;
  const float* gb = gen + (size_t)b * VV;
  const float* cb = cvals + (size_t)b * VV;
  const int* ct = cnt + (size_t)b * VV;
  // pass 1: max over all 2V+S logits (extended slots are NEGV, never the max)
  float m = -3.4e38f;
  for (int v = tid; v < VV; v += 256) {
    const float gv = (v == 0) ? NEGV : gb[v];
    const float cv = (v == 0 || ct[v] == 0) ? NEGV : cb[v];
    m = fmaxf(m, fmaxf(gv, cv));
  }
  s_red[tid] = m;
  __syncthreads();
  for (int o = 128; o; o >>= 1) {
    if (tid < o) s_red[tid] = fmaxf(s_red[tid], s_red[tid + o]);
    __syncthreads();
  }
  m = s_red[0];
  __syncthreads();
  // pass 2: denominator (NEGV slots contribute exactly 0 in fp32, matching ref)
  float sm = 0.f;
  for (int v = tid; v < VV; v += 256) {
    const float gv = (v == 0) ? NEGV : gb[v];
    const float cv = (v == 0 || ct[v] == 0) ? NEGV : cb[v];
    sm += expf(gv - m) + expf(cv - m);
  }
  s_red[tid] = sm;
  __syncthreads();
  for (int o = 128; o; o >>= 1) {
    if (tid < o) s_red[tid] += s_red[tid + o];
    __syncthreads();
  }
  const float inv = 1.f / s_red[0];
  __syncthreads();
  // pass 3: final probs -> log -> write + argmax (first-index tie-break)
  float bv = -3.4e38f;
  int bi = VSS;
  float* ob = out + ((size_t)t * BB + b) * VSS;
  for (int v = tid; v < VV; v += 256) {
    const float gv = (v == 0) ? NEGV : gb[v];
    const float cv = (v == 0 || ct[v] == 0) ? NEGV : cb[v];
    const float p = expf(gv - m) * inv + expf(cv - m) * inv;
    const float lp = logf(p + 1e-10f);
    ob[v] = lp;
    if (lp > bv) { bv = lp; bi = v; }  // strictly >, v ascending: keeps first max
  }
  const float lpz = logf(1e-10f);  // extended-vocab slots: prob exactly 0
  for (int j = VV + tid; j < VSS; j += 256) ob[j] = lpz;
  s_red[tid] = bv;
  s_idx[tid] = bi;
  __syncthreads();
  for (int o = 128; o; o >>= 1) {
    if (tid < o) {
      const float ov = s_red[tid + o];
      const int oi = s_idx[tid + o];
      if (ov > s_red[tid] || (ov == s_red[tid] && oi < s_idx[tid])) {
        s_red[tid] = ov;
        s_idx[tid] = oi;
      }
    }
    __syncthreads();
  }
  const int sp = s_idx[0];
  if (tid == 0) {
    samp[b] = sp;
    out[(size_t)TT * BB * VSS + (size_t)b * TT + t] = (float)sp;
  }
  __syncthreads();
  // selective read: selected = (inp==sp)*cseq ; norm ; sel_new = norm @ enc
  float sv = 0.f;
  if (tid < SS) sv = (inp[b * SS + tid] == sp) ? cseq[b * SS + tid] : 0.f;
  s_red[tid] = fabsf(sv);
  __syncthreads();
  for (int o = 128; o; o >>= 1) {
    if (tid < o) s_red[tid] += s_red[tid + o];
    __syncthreads();
  }
  const float nf = 1.f / fmaxf(s_red[0], 1e-12f);
  __syncthreads();
  if (tid < SS) s_norm[tid] = sv * nf;
  __syncthreads();
  const float4* eb = (const float4*)(enc + (size_t)b * SS * HH);
  float4 acc = make_float4(0.f, 0.f, 0.f, 0.f);
  for (int s = 0; s < SS; ++s) {
    const float a = s_norm[s];
    if (a != 0.f) {
      const float4 x = eb[s * (HH / 4) + tid];
      acc.x += a * x.x; acc.y += a * x.y; acc.z += a * x.z; acc.w += a * x.w;
    }
  }
  ((float4*)(seln + b * HH))[tid] = acc;
}

extern "C" void kernel_launch(void* const* d_in, const int* in_sizes, int n_in,
                              void* d_out, int out_size, void* d_ws, size_t ws_size,
                              hipStream_t stream) {
  const int* inp = (const int*)d_in[0];
  const float* hidden = (const float*)d_in[1];
  const float* enc = (const float*)d_in[2];
  // d_in[3] = max_length (known fixed: 48)
  const float* Wa = (const float*)d_in[4];
  const float* ba = (const float*)d_in[5];
  const float* Wc = (const float*)d_in[6];
  const float* bc = (const float*)d_in[7];
  const float* emb = (const float*)d_in[8];
  const float* Wih = (const float*)d_in[9];
  const float* Whh = (const float*)d_in[10];
  const float* bih = (const float*)d_in[11];
  const float* bhh = (const float*)d_in[12];
  const float* Wo = (const float*)d_in[13];
  const float* bo = (const float*)d_in[14];
  float* out = (float*)d_out;

  float* ws = (float*)d_ws;
  float* hb0 = ws;                    // [B*H]
  float* hb1 = hb0 + BB * HH;         // [B*H]
  float* sb0 = hb1 + BB * HH;         // [B*H]
  float* sb1 = sb0 + BB * HH;         // [B*H]
  float* ctx = sb1 + BB * HH;         // [B*H]
  float* cseq = ctx + BB * HH;        // [B*S]
  float* gen = cseq + BB * SS;        // [B*V]
  float* cvals = gen + (size_t)BB * VV;   // [B*V]
  int* cnt = (int*)(cvals + (size_t)BB * VV);  // [B*V]
  int* samp = cnt + (size_t)BB * VV;  // [B]

  k_init<<<(BB * VSS + 255) / 256, 256, 0, stream>>>(out, sb0, cnt, samp);
  k_count<<<(BB * SS + 255) / 256, 256, 0, stream>>>(inp, cnt);

  for (int t = 1; t < TT; ++t) {
    const float* hc = (t == 1) ? hidden : (((t - 1) & 1) ? hb0 : hb1);
    float* hw = (t & 1) ? hb0 : hb1;
    const float* sr = (t == 1) ? sb0 : (((t - 1) & 1) ? sb1 : sb0);
    float* sw = (t & 1) ? sb1 : sb0;

    k_attn<<<BB, 256, 0, stream>>>(hc, Wa, ba, enc, ctx);
    k_gru<<<BB * HH / 256, 256, 0, stream>>>(hc, ctx, sr, emb, samp, Wih, Whh, bih, bhh, hw);
    k_copy<<<BB, 256, 0, stream>>>(hw, Wc, bc, enc, inp, cseq, cvals);
    k_gen<<<BB * VV / 256, 256, 0, stream>>>(hw, Wo, bo, gen);
    k_out<<<BB, 256, 0, stream>>>(gen, cvals, cnt, cseq, inp, enc, out, sw, samp, t);
  }
}

// Round 4
// 28482.901 us; speedup vs baseline: 1.8118x; 1.8118x over previous
//
#include <hip/hip_runtime.h>

#define BB 32
#define SS 128
#define HH 1024
#define EE 256
#define VV 16000
#define TT 48
#define VSS (VV + SS)
#define GIN 2304
#define NEGV (-1000000.0f)

__device__ __forceinline__ float dot4(float4 a, float4 b) {
  return a.x * b.x + a.y * b.y + a.z * b.z + a.w * b.w;
}

__device__ __forceinline__ float wave_reduce_sum(float v) {
  for (int o = 32; o; o >>= 1) v += __shfl_down(v, o, 64);
  return v;
}

// ---------------- init: SOS row = 2.0, ids[:,0]=1, sampled=1, sel0=0 ---------------
__global__ __launch_bounds__(256) void k_init(float* __restrict__ out,
                                              float* __restrict__ sel0,
                                              int* __restrict__ samp) {
  const int i = blockIdx.x * 256 + threadIdx.x;
  if (i < BB * VSS) out[i] = 2.0f;
  if (i < BB * HH) sel0[i] = 0.0f;
  if (i < BB) {
    samp[i] = 1;
    out[(size_t)TT * BB * VSS + (size_t)i * TT] = 1.0f;
  }
}

__global__ __launch_bounds__(256) void k_count(const int* __restrict__ inp,
                                               unsigned* __restrict__ mask) {
  const int i = blockIdx.x * 256 + threadIdx.x;
  if (i < BB * SS) {
    const int b = i / SS;
    atomicOr(&mask[inp[i]], 1u << b);
  }
}

// ---------------- th GEMV: th[b][j] = W[j]·h[b] + bias[j] --------------------------
// Preserves round-1 per-j numerics exactly: lane-strided dot4 partials (k=lane;
// k<256; k+=64) + 64-lane shfl_down tree. Only the j->wave/block map changed.
// grid 256 = 32 b x 8 sub-blocks; each wave computes 32 consecutive j.
__global__ __launch_bounds__(256) void k_th(const float* __restrict__ W,
                                            const float* __restrict__ bias,
                                            const float* __restrict__ hvec,
                                            float* __restrict__ thout) {
  __shared__ float s_h[HH];
  const int blk = blockIdx.x, tid = threadIdx.x;
  const int b = blk >> 3, bb = blk & 7;
  const int lane = tid & 63, wv = tid >> 6;
  for (int i = tid; i < HH; i += 256) s_h[i] = hvec[b * HH + i];
  __syncthreads();
  const float4* h4 = (const float4*)s_h;
  const int j0 = bb * 128 + wv * 32;
  for (int i = 0; i < 32; ++i) {
    const int j = j0 + i;
    const float4* wr = (const float4*)(W + (size_t)j * HH);
    float acc = 0.f;
#pragma unroll 4
    for (int k = lane; k < HH / 4; k += 64) acc += dot4(wr[k], h4[k]);
    acc = wave_reduce_sum(acc);
    if (lane == 0) thout[b * HH + j] = acc + bias[j];
  }
}

// ---------------- attention part 2: scores, softmax, context (round-1 verbatim) ----
__global__ __launch_bounds__(256) void k_attn2(const float* __restrict__ th,
                                               const float* __restrict__ enc,
                                               float* __restrict__ ctx) {
  __shared__ float s_th[HH];
  __shared__ float s_sc[SS];
  __shared__ float s_red[256];
  const int b = blockIdx.x, tid = threadIdx.x;
  const int lane = tid & 63, wv = tid >> 6;
  for (int i = tid; i < HH; i += 256) s_th[i] = th[b * HH + i];
  __syncthreads();
  const float4* th4 = (const float4*)s_th;
  for (int s = wv; s < SS; s += 4) {
    const float4* er = (const float4*)(enc + ((size_t)b * SS + s) * HH);
    float acc = 0.f;
#pragma unroll 4
    for (int k = lane; k < HH / 4; k += 64) acc += dot4(er[k], th4[k]);
    acc = wave_reduce_sum(acc);
    if (lane == 0) s_sc[s] = acc;
  }
  __syncthreads();
  const float v = (tid < SS) ? s_sc[tid] : -3.4e38f;
  s_red[tid] = v;
  __syncthreads();
  for (int o = 128; o; o >>= 1) {
    if (tid < o) s_red[tid] = fmaxf(s_red[tid], s_red[tid + o]);
    __syncthreads();
  }
  const float m = s_red[0];
  __syncthreads();
  const float e = (tid < SS) ? expf(v - m) : 0.f;
  s_red[tid] = e;
  __syncthreads();
  for (int o = 128; o; o >>= 1) {
    if (tid < o) s_red[tid] += s_red[tid + o];
    __syncthreads();
  }
  const float den = s_red[0];
  __syncthreads();
  if (tid < SS) s_sc[tid] = e / den;
  __syncthreads();
  const float4* eb = (const float4*)(enc + (size_t)b * SS * HH);
  float4 acc = make_float4(0.f, 0.f, 0.f, 0.f);
  for (int s = 0; s < SS; ++s) {
    const float a = s_sc[s];
    const float4 x = eb[s * (HH / 4) + tid];
    acc.x += a * x.x; acc.y += a * x.y; acc.z += a * x.z; acc.w += a * x.w;
  }
  ((float4*)(ctx + b * HH))[tid] = acc;
}

// ---------------- GRU chains: 6 independent serial chains per (b,j) ----------------
// Each chain's accumulation order is identical to round 1's k_gru (ctx,sel,emb
// sequential for ih; hc for hh; bias added after the full sum). Only the chain->
// thread mapping changed (6x more parallelism, j-major lanes for coalescing).
// grid 768: c = blk/128 (0..5), b = (blk%128)>>2, j = (blk&3)*256 + tid.
__global__ __launch_bounds__(256) void k_gru2(const float* __restrict__ hc,
                                              const float* __restrict__ ctx,
                                              const float* __restrict__ sel,
                                              const float* __restrict__ embt,
                                              const int* __restrict__ samp,
                                              const float* __restrict__ Wih,
                                              const float* __restrict__ Whh,
                                              const float* __restrict__ bih,
                                              const float* __restrict__ bhh,
                                              float* __restrict__ gbuf) {
  const int blk = blockIdx.x, tid = threadIdx.x;
  const int c = blk >> 7;
  const int r = blk & 127;
  const int b = r >> 2;
  const int j = (r & 3) * 256 + tid;
  float a = 0.f;
  if (c < 3) {
    const float4* wi = (const float4*)(Wih + (size_t)(c * HH + j) * GIN);
    int p = samp[b];
    int ei = (p > VV) ? 3 : p;  // strict >, as in source
    if (ei >= VV) ei = VV - 1;  // jnp OOB gather clamps
    const float4* xc = (const float4*)(ctx + b * HH);
    const float4* xs = (const float4*)(sel + b * HH);
    const float4* xe = (const float4*)(embt + (size_t)ei * EE);
#pragma unroll 8
    for (int k = 0; k < HH / 4; ++k) a += dot4(wi[k], xc[k]);
#pragma unroll 8
    for (int k = 0; k < HH / 4; ++k) a += dot4(wi[HH / 4 + k], xs[k]);
#pragma unroll 8
    for (int k = 0; k < EE / 4; ++k) a += dot4(wi[2 * (HH / 4) + k], xe[k]);
    a += bih[c * HH + j];
  } else {
    const int g = c - 3;
    const float4* wh = (const float4*)(Whh + (size_t)(g * HH + j) * HH);
    const float4* h4 = (const float4*)(hc + b * HH);
#pragma unroll 8
    for (int k = 0; k < HH / 4; ++k) a += dot4(wh[k], h4[k]);
    a += bhh[g * HH + j];
  }
  gbuf[(size_t)c * (BB * HH) + b * HH + j] = a;
}

__global__ __launch_bounds__(256) void k_grufin(const float* __restrict__ gbuf,
                                                const float* __restrict__ hc,
                                                float* __restrict__ hn) {
  const int gid = blockIdx.x * 256 + threadIdx.x;
  const int b = gid >> 10, j = gid & 1023;
  const int o = b * HH + j;
  const float gxr = gbuf[0 * (BB * HH) + o];
  const float gxz = gbuf[1 * (BB * HH) + o];
  const float gxn = gbuf[2 * (BB * HH) + o];
  const float ghr = gbuf[3 * (BB * HH) + o];
  const float ghz = gbuf[4 * (BB * HH) + o];
  const float ghn = gbuf[5 * (BB * HH) + o];
  const float rr = 1.f / (1.f + expf(-(gxr + ghr)));
  const float zz = 1.f / (1.f + expf(-(gxz + ghz)));
  const float nn = tanhf(gxn + rr * ghn);
  hn[o] = (1.f - zz) * nn + zz * hc[o];
}

// ---------------- copy part 2: cseq = enc.th2 ; zero + scatter (round-1 verbatim) --
__global__ __launch_bounds__(256) void k_copy2(const float* __restrict__ th2,
                                               const float* __restrict__ enc,
                                               const int* __restrict__ inp,
                                               float* __restrict__ cseq,
                                               float* __restrict__ cvals) {
  __shared__ float s_th[HH];
  __shared__ float s_sc[SS];
  const int b = blockIdx.x, tid = threadIdx.x;
  const int lane = tid & 63, wv = tid >> 6;
  for (int i = tid; i < HH; i += 256) s_th[i] = th2[b * HH + i];
  __syncthreads();
  const float4* th4 = (const float4*)s_th;
  for (int s = wv; s < SS; s += 4) {
    const float4* er = (const float4*)(enc + ((size_t)b * SS + s) * HH);
    float acc = 0.f;
#pragma unroll 4
    for (int k = lane; k < HH / 4; k += 64) acc += dot4(er[k], th4[k]);
    acc = wave_reduce_sum(acc);
    if (lane == 0) {
      s_sc[s] = acc;
      cseq[b * SS + s] = acc;
    }
  }
  for (int i = tid; i < VV; i += 256) cvals[(size_t)b * VV + i] = 0.f;
  __syncthreads();
  if (tid < SS) atomicAdd(&cvals[(size_t)b * VV + inp[b * SS + tid]], s_sc[tid]);
}

// ---------------- generate logits (round-1 verbatim) -------------------------------
__global__ __launch_bounds__(256) void k_gen(const float* __restrict__ hn,
                                             const float* __restrict__ Wo,
                                             const float* __restrict__ bo,
                                             float* __restrict__ gen) {
  const int gid = blockIdx.x * 256 + threadIdx.x;  // B*V threads
  const int b = gid & 31, v = gid >> 5;
  const float4* wr = (const float4*)(Wo + (size_t)v * HH);
  const float4* hr = (const float4*)(hn + b * HH);
  float a = 0.f;
#pragma unroll 4
  for (int k = 0; k < HH / 4; ++k) a += dot4(wr[k], hr[k]);
  gen[(size_t)b * VV + v] = a + bo[v];
}

// ---------------- softmax/log/argmax/sel-read (round-1 verbatim; cnt->bitmask) -----
__global__ __launch_bounds__(256) void k_out(const float* __restrict__ gen,
                                             const float* __restrict__ cvals,
                                             const unsigned* __restrict__ mask,
                                             const float* __restrict__ cseq,
                                             const int* __restrict__ inp,
                                             const float* __restrict__ enc,
                                             float* __restrict__ out,
                                             float* __restrict__ seln,
                                             int* __restrict__ samp,
                                             const int t) {
  __shared__ float s_red[256];
  __shared__ int s_idx[256];
  __shared__ float s_norm[SS];
  const int b = blockIdx.x, tid = threadIdx.x;
  const float* gb = gen + (size_t)b * VV;
  const float* cb = cvals + (size_t)b * VV;
  // pass 1: max over all logits (extended slots are NEGV, never the max)
  float m = -3.4e38f;
  for (int v = tid; v < VV; v += 256) {
    const float gv = (v == 0) ? NEGV : gb[v];
    const float cv = (v == 0 || !((mask[v] >> b) & 1u)) ? NEGV : cb[v];
    m = fmaxf(m, fmaxf(gv, cv));
  }
  s_red[tid] = m;
  __syncthreads();
  for (int o = 128; o; o >>= 1) {
    if (tid < o) s_red[tid] = fmaxf(s_red[tid], s_red[tid + o]);
    __syncthreads();
  }
  m = s_red[0];
  __syncthreads();
  // pass 2: denominator (NEGV slots contribute exactly 0 in fp32)
  float sm = 0.f;
  for (int v = tid; v < VV; v += 256) {
    const float gv = (v == 0) ? NEGV : gb[v];
    const float cv = (v == 0 || !((mask[v] >> b) & 1u)) ? NEGV : cb[v];
    sm += expf(gv - m) + expf(cv - m);
  }
  s_red[tid] = sm;
  __syncthreads();
  for (int o = 128; o; o >>= 1) {
    if (tid < o) s_red[tid] += s_red[tid + o];
    __syncthreads();
  }
  const float inv = 1.f / s_red[0];
  __syncthreads();
  // pass 3: probs -> log -> write + argmax (first-index tie-break)
  float bv = -3.4e38f;
  int bi = VSS;
  float* ob = out + ((size_t)t * BB + b) * VSS;
  for (int v = tid; v < VV; v += 256) {
    const float gv = (v == 0) ? NEGV : gb[v];
    const float cv = (v == 0 || !((mask[v] >> b) & 1u)) ? NEGV : cb[v];
    const float p = expf(gv - m) * inv + expf(cv - m) * inv;
    const float lp = logf(p + 1e-10f);
    ob[v] = lp;
    if (lp > bv) { bv = lp; bi = v; }
  }
  const float lpz = logf(1e-10f);  // extended-vocab slots: prob exactly 0
  for (int j = VV + tid; j < VSS; j += 256) ob[j] = lpz;
  s_red[tid] = bv;
  s_idx[tid] = bi;
  __syncthreads();
  for (int o = 128; o; o >>= 1) {
    if (tid < o) {
      const float ov = s_red[tid + o];
      const int oi = s_idx[tid + o];
      if (ov > s_red[tid] || (ov == s_red[tid] && oi < s_idx[tid])) {
        s_red[tid] = ov;
        s_idx[tid] = oi;
      }
    }
    __syncthreads();
  }
  const int sp = s_idx[0];
  if (tid == 0) {
    samp[b] = sp;
    out[(size_t)TT * BB * VSS + (size_t)b * TT + t] = (float)sp;
  }
  __syncthreads();
  // selective read: selected = (inp==sp)*cseq ; norm ; sel_new = norm @ enc
  float sv = 0.f;
  if (tid < SS) sv = (inp[b * SS + tid] == sp) ? cseq[b * SS + tid] : 0.f;
  s_red[tid] = fabsf(sv);
  __syncthreads();
  for (int o = 128; o; o >>= 1) {
    if (tid < o) s_red[tid] += s_red[tid + o];
    __syncthreads();
  }
  const float nf = 1.f / fmaxf(s_red[0], 1e-12f);
  __syncthreads();
  if (tid < SS) s_norm[tid] = sv * nf;
  __syncthreads();
  const float4* eb = (const float4*)(enc + (size_t)b * SS * HH);
  float4 acc = make_float4(0.f, 0.f, 0.f, 0.f);
  for (int s = 0; s < SS; ++s) {
    const float a = s_norm[s];
    if (a != 0.f) {
      const float4 x = eb[s * (HH / 4) + tid];
      acc.x += a * x.x; acc.y += a * x.y; acc.z += a * x.z; acc.w += a * x.w;
    }
  }
  ((float4*)(seln + b * HH))[tid] = acc;
}

extern "C" void kernel_launch(void* const* d_in, const int* in_sizes, int n_in,
                              void* d_out, int out_size, void* d_ws, size_t ws_size,
                              hipStream_t stream) {
  const int* inp = (const int*)d_in[0];
  const float* hidden = (const float*)d_in[1];
  const float* enc = (const float*)d_in[2];
  const float* Wa = (const float*)d_in[4];
  const float* ba = (const float*)d_in[5];
  const float* Wc = (const float*)d_in[6];
  const float* bc = (const float*)d_in[7];
  const float* emb = (const float*)d_in[8];
  const float* Wih = (const float*)d_in[9];
  const float* Whh = (const float*)d_in[10];
  const float* bih = (const float*)d_in[11];
  const float* bhh = (const float*)d_in[12];
  const float* Wo = (const float*)d_in[13];
  const float* bo = (const float*)d_in[14];
  float* out = (float*)d_out;

  // ws ~5.9 MB, below round-1's proven 6.8 MB footprint
  float* ws = (float*)d_ws;
  float* hb0 = ws;                        // [B*H]
  float* hb1 = hb0 + BB * HH;             // [B*H]
  float* sb0 = hb1 + BB * HH;             // [B*H]
  float* sb1 = sb0 + BB * HH;             // [B*H]
  float* ctx = sb1 + BB * HH;             // [B*H]
  float* th = ctx + BB * HH;              // [B*H]
  float* th2 = th + BB * HH;              // [B*H]
  float* gbuf = th2 + BB * HH;            // [6*B*H]
  float* cseq = gbuf + 6 * BB * HH;       // [B*S]
  float* gen = cseq + BB * SS;            // [B*V]
  float* cvals = gen + (size_t)BB * VV;   // [B*V]
  unsigned* mask = (unsigned*)(cvals + (size_t)BB * VV);  // [V]
  int* samp = (int*)(mask + VV);          // [B]

  hipMemsetAsync(mask, 0, (size_t)VV * 4, stream);
  k_init<<<(BB * VSS + 255) / 256, 256, 0, stream>>>(out, sb0, samp);
  k_count<<<(BB * SS + 255) / 256, 256, 0, stream>>>(inp, mask);

  for (int t = 1; t < TT; ++t) {
    const float* hc = (t == 1) ? hidden : (((t - 1) & 1) ? hb0 : hb1);
    float* hw = (t & 1) ? hb0 : hb1;
    const float* sr = (t == 1) ? sb0 : (((t - 1) & 1) ? sb1 : sb0);
    float* sw = (t & 1) ? sb1 : sb0;

    k_th<<<BB * 8, 256, 0, stream>>>(Wa, ba, hc, th);
    k_attn2<<<BB, 256, 0, stream>>>(th, enc, ctx);
    k_gru2<<<6 * 128, 256, 0, stream>>>(hc, ctx, sr, emb, samp, Wih, Whh, bih, bhh,
                                        gbuf);
    k_grufin<<<BB * HH / 256, 256, 0, stream>>>(gbuf, hc, hw);
    k_th<<<BB * 8, 256, 0, stream>>>(Wc, bc, hw, th2);
    k_copy2<<<BB, 256, 0, stream>>>(th2, enc, inp, cseq, cvals);
    k_gen<<<BB * VV / 256, 256, 0, stream>>>(hw, Wo, bo, gen);
    k_out<<<BB, 256, 0, stream>>>(gen, cvals, mask, cseq, inp, enc, out, sw, samp, t);
  }
}